// Round 1
// baseline (1317.689 us; speedup 1.0000x reference)
//
#include <hip/hip_runtime.h>

// BCQ (LUT-GEMM style) linear: out[:, out_reorder] = x[:, in_reorder] @ W
// W[k,n] = alpha[k/128, n] * wsum[k,n] + beta[k/128, n]
// wsum[k,n] = 2*val - (2^nb - 1), val = bits of planes b < nb = block_bitwidth[k/128, n/32]
//
// Strategy: split-precision bf16 MFMA GEMM (x_hi*W_hi + x_lo*W_hi + x_hi*W_lo),
// permutations folded into prep kernels. Workspace: xh(64M) xl(64M) Wth(32M) Wtl(32M) inv_out(16K).

typedef unsigned short u16;
typedef unsigned int u32;
typedef __attribute__((ext_vector_type(8))) short bf16x8;
typedef __attribute__((ext_vector_type(4))) float f32x4;

#define M_DIM 8192
#define K_DIM 4096
#define N_DIM 4096

__device__ __forceinline__ u16 f2bf(float f) {
  u32 u = __float_as_uint(f);
  u32 r = (u + 0x7fffu + ((u >> 16) & 1u)) >> 16;   // RNE
  return (u16)r;
}
__device__ __forceinline__ float bf2f(u16 h) { return __uint_as_float(((u32)h) << 16); }

__device__ __forceinline__ void load_lds16(const void* g, void* l) {
  __builtin_amdgcn_global_load_lds((const __attribute__((address_space(1))) void*)g,
                                   (__attribute__((address_space(3))) void*)l, 16, 0, 0);
}

// ---------------- inverse permutation of out_reorder ----------------
__global__ void invert_kernel(const int* __restrict__ out_reorder, int* __restrict__ inv_out) {
  int i = blockIdx.x * 256 + threadIdx.x;
  if (i < N_DIM) inv_out[out_reorder[i]] = i;
}

// ---------------- x gather (in_reorder) + bf16 hi/lo split ----------------
// xh[m][k] = bf16(x[m][in_reorder[k]]), xl = bf16(residual)
__global__ void convert_x_kernel(const float* __restrict__ x, const int* __restrict__ inr,
                                 u16* __restrict__ xh, u16* __restrict__ xl) {
  const int m = blockIdx.x;
  const float* __restrict__ xrow = x + (long)m * K_DIM;
  for (int base = threadIdx.x * 8; base < K_DIM; base += 256 * 8) {
    u32 oh[4] = {0, 0, 0, 0}, ol[4] = {0, 0, 0, 0};
#pragma unroll
    for (int i = 0; i < 8; ++i) {
      float v = xrow[inr[base + i]];
      u16 h = f2bf(v);
      u16 l = f2bf(v - bf2f(h));
      oh[i >> 1] |= ((u32)h) << ((i & 1) * 16);
      ol[i >> 1] |= ((u32)l) << ((i & 1) * 16);
    }
    long o = (long)m * K_DIM + base;
    *(uint4*)&xh[o] = *(const uint4*)oh;
    *(uint4*)&xl[o] = *(const uint4*)ol;
  }
}

// ---------------- W dequant into K-major, out-permuted, bf16 hi/lo split ----------------
// Wt{h,l}[nc][k] = bf16 split of W[k][inv_out[nc]]
// block = one output column nc (128 threads, one per 32-k word); writes 64B contiguous/thread.
__global__ void dequant_kernel(const u32* __restrict__ qw, const float* __restrict__ alpha,
                               const float* __restrict__ beta, const int* __restrict__ inv_out,
                               const int* __restrict__ bbw,
                               u16* __restrict__ wth, u16* __restrict__ wtl) {
  const int nc = blockIdx.x;
  const int kw = threadIdx.x;          // 0..127 : word index along k (32 k per word)
  const int n = inv_out[nc];
  const int g = kw >> 2;               // input group = (kw*32)/128
  const int nb = bbw[g * 128 + (n >> 5)];
  const float a = alpha[g * N_DIM + n];
  const float bt = beta[g * N_DIM + n];
  const u32 q0 = qw[(kw * 4 + 0) * N_DIM + n];
  u32 q1 = qw[(kw * 4 + 1) * N_DIM + n];
  u32 q2 = qw[(kw * 4 + 2) * N_DIM + n];
  u32 q3 = qw[(kw * 4 + 3) * N_DIM + n];
  q1 = (nb > 1) ? q1 : 0u;
  q2 = (nb > 2) ? q2 : 0u;
  q3 = (nb > 3) ? q3 : 0u;
  const float a2 = 2.0f * a;
  const float offs = bt - a * (float)((1 << nb) - 1);   // beta - alpha*(2^nb - 1)

  __align__(16) u32 oh[16], ol[16];
#pragma unroll
  for (int j = 0; j < 16; ++j) { oh[j] = 0u; ol[j] = 0u; }
#pragma unroll
  for (int j = 0; j < 32; ++j) {
    u32 val = ((q0 >> j) & 1u) | (((q1 >> j) & 1u) << 1) |
              (((q2 >> j) & 1u) << 2) | (((q3 >> j) & 1u) << 3);
    float wv = a2 * (float)val + offs;
    u16 h = f2bf(wv);
    u16 l = f2bf(wv - bf2f(h));
    oh[j >> 1] |= ((u32)h) << ((j & 1) * 16);
    ol[j >> 1] |= ((u32)l) << ((j & 1) * 16);
  }
  long basee = (long)nc * K_DIM + kw * 32;
  uint4* dh = (uint4*)&wth[basee];
  uint4* dl = (uint4*)&wtl[basee];
#pragma unroll
  for (int i = 0; i < 4; ++i) {
    dh[i] = ((const uint4*)oh)[i];
    dl[i] = ((const uint4*)ol)[i];
  }
}

// ---------------- GEMM: C = xh@Wh + xl@Wh + xh@Wl (B given K-major) ----------------
// 128x128 tile, 4 waves (2x2 of 64x64 each), BK=32, single-buffer LDS via global_load_lds(16B).
__global__ void gemm_kernel(const u16* __restrict__ xh, const u16* __restrict__ xl,
                            const u16* __restrict__ wth, const u16* __restrict__ wtl,
                            float* __restrict__ out) {
  __shared__ __align__(16) u16 As[128 * 32];   // [row][k]
  __shared__ __align__(16) u16 Bs[128 * 32];   // [col][k]  (B is K-major per column)

  const int tid = threadIdx.x;
  const int lane = tid & 63;
  const int wave = tid >> 6;
  const long brow = (long)blockIdx.y * 128;
  const long bcol = (long)blockIdx.x * 128;
  const int wr = (wave >> 1) * 64;   // wave's row offset within tile
  const int wc = (wave & 1) * 64;    // wave's col offset within tile

  f32x4 acc[4][4];
  const f32x4 zero = {0.f, 0.f, 0.f, 0.f};
#pragma unroll
  for (int i = 0; i < 4; ++i)
#pragma unroll
    for (int j = 0; j < 4; ++j) acc[i][j] = zero;

  // staging: chunk c = tid covers (row c>>2, 8 k's at (c&3)*8); second chunk = c+256
  const int sr = tid >> 2;
  const int sk = (tid & 3) * 8;
  const int fr = lane & 15;            // fragment row/col
  const int fk = (lane >> 4) * 8;      // fragment k offset

  for (int seg = 0; seg < 3; ++seg) {
    const u16* __restrict__ A = ((seg == 1) ? xl : xh) + brow * K_DIM;
    const u16* __restrict__ B = ((seg == 2) ? wtl : wth) + bcol * K_DIM;
    for (int kt = 0; kt < K_DIM / 32; ++kt) {
      const int k0 = kt * 32;
      __syncthreads();   // previous tile fully consumed
      load_lds16(A + (long)sr * K_DIM + k0 + sk,        &As[wave * 512]);
      load_lds16(A + (long)(sr + 64) * K_DIM + k0 + sk, &As[2048 + wave * 512]);
      load_lds16(B + (long)sr * K_DIM + k0 + sk,        &Bs[wave * 512]);
      load_lds16(B + (long)(sr + 64) * K_DIM + k0 + sk, &Bs[2048 + wave * 512]);
      __syncthreads();   // compiler drains vmcnt(0) before s_barrier

      bf16x8 a[4], b[4];
#pragma unroll
      for (int m = 0; m < 4; ++m)
        a[m] = *(const bf16x8*)&As[(wr + m * 16 + fr) * 32 + fk];
#pragma unroll
      for (int n = 0; n < 4; ++n)
        b[n] = *(const bf16x8*)&Bs[(wc + n * 16 + fr) * 32 + fk];
#pragma unroll
      for (int m = 0; m < 4; ++m)
#pragma unroll
        for (int n = 0; n < 4; ++n)
          acc[m][n] = __builtin_amdgcn_mfma_f32_16x16x32_bf16(a[m], b[n], acc[m][n], 0, 0, 0);
    }
  }

  // epilogue: C/D layout col=lane&15, row=(lane>>4)*4+r   [verified mapping]
  const int orow = (lane >> 4) * 4;
  const int ocol = lane & 15;
#pragma unroll
  for (int m = 0; m < 4; ++m)
#pragma unroll
    for (int n = 0; n < 4; ++n) {
      long r0 = brow + wr + m * 16 + orow;
      long c0 = bcol + wc + n * 16 + ocol;
#pragma unroll
      for (int r = 0; r < 4; ++r)
        out[(r0 + r) * N_DIM + c0] = acc[m][n][r];
    }
}

extern "C" void kernel_launch(void* const* d_in, const int* in_sizes, int n_in,
                              void* d_out, int out_size, void* d_ws, size_t ws_size,
                              hipStream_t stream) {
  const float* x = (const float*)d_in[0];
  const u32* qweight = (const u32*)d_in[1];
  const float* alpha = (const float*)d_in[2];
  const float* beta = (const float*)d_in[3];
  const int* in_reorder = (const int*)d_in[4];
  const int* out_reorder = (const int*)d_in[5];
  const int* bbw = (const int*)d_in[6];
  float* out = (float*)d_out;

  char* ws = (char*)d_ws;
  u16* xh = (u16*)(ws);                               // 64 MiB
  u16* xl = (u16*)(ws + ((size_t)64 << 20));          // 64 MiB
  u16* wth = (u16*)(ws + ((size_t)128 << 20));        // 32 MiB
  u16* wtl = (u16*)(ws + ((size_t)160 << 20));        // 32 MiB
  int* inv_out = (int*)(ws + ((size_t)192 << 20));    // 16 KiB

  hipLaunchKernelGGL(invert_kernel, dim3(16), dim3(256), 0, stream, out_reorder, inv_out);
  hipLaunchKernelGGL(convert_x_kernel, dim3(M_DIM), dim3(256), 0, stream, x, in_reorder, xh, xl);
  hipLaunchKernelGGL(dequant_kernel, dim3(N_DIM), dim3(128), 0, stream,
                     qweight, alpha, beta, inv_out, bbw, wth, wtl);
  hipLaunchKernelGGL(gemm_kernel, dim3(N_DIM / 128, M_DIM / 128), dim3(256), 0, stream,
                     xh, xl, wth, wtl, out);
}

// Round 2
// 922.936 us; speedup vs baseline: 1.4277x; 1.4277x over previous
//
#include <hip/hip_runtime.h>

// BCQ (LUT-GEMM style) linear: out[:, out_reorder] = x[:, in_reorder] @ W
// W[k,n] = alpha[k/128, n] * wsum[k,n] + beta[k/128, n]
// Split-precision bf16 MFMA GEMM: y = xh@Wh + xl@Wh + xh@Wl (3-segment flat K-stream).
// GEMM = 256x256 tile, BK=64, 8 waves, 4-phase/K-tile schedule with counted vmcnt(4),
// T2 LDS XOR-swizzle, T5 setprio. Race ledger in comments below.

typedef unsigned short u16;
typedef unsigned int u32;
typedef __attribute__((ext_vector_type(8))) short bf16x8;
typedef __attribute__((ext_vector_type(4))) float f32x4;

#define M_DIM 8192
#define K_DIM 4096
#define N_DIM 4096
#define NTILES 192   // 3 segments * (4096/64)

__device__ __forceinline__ u16 f2bf(float f) {
  u32 u = __float_as_uint(f);
  u32 r = (u + 0x7fffu + ((u >> 16) & 1u)) >> 16;   // RNE
  return (u16)r;
}
__device__ __forceinline__ float bf2f(u16 h) { return __uint_as_float(((u32)h) << 16); }

__device__ __forceinline__ void load_lds16(const void* g, void* l) {
  __builtin_amdgcn_global_load_lds((const __attribute__((address_space(1))) void*)g,
                                   (__attribute__((address_space(3))) void*)l, 16, 0, 0);
}

// ---------------- inverse permutation of out_reorder ----------------
__global__ void invert_kernel(const int* __restrict__ out_reorder, int* __restrict__ inv_out) {
  int i = blockIdx.x * 256 + threadIdx.x;
  if (i < N_DIM) inv_out[out_reorder[i]] = i;
}

// ---------------- x gather (in_reorder) + bf16 hi/lo split ----------------
__global__ void convert_x_kernel(const float* __restrict__ x, const int* __restrict__ inr,
                                 u16* __restrict__ xh, u16* __restrict__ xl) {
  const int m = blockIdx.x;
  const float* __restrict__ xrow = x + (long)m * K_DIM;
  for (int base = threadIdx.x * 8; base < K_DIM; base += 256 * 8) {
    u32 oh[4] = {0, 0, 0, 0}, ol[4] = {0, 0, 0, 0};
#pragma unroll
    for (int i = 0; i < 8; ++i) {
      float v = xrow[inr[base + i]];
      u16 h = f2bf(v);
      u16 l = f2bf(v - bf2f(h));
      oh[i >> 1] |= ((u32)h) << ((i & 1) * 16);
      ol[i >> 1] |= ((u32)l) << ((i & 1) * 16);
    }
    long o = (long)m * K_DIM + base;
    *(uint4*)&xh[o] = *(const uint4*)oh;
    *(uint4*)&xl[o] = *(const uint4*)ol;
  }
}

// ---------------- W dequant into K-major, out-permuted, bf16 hi/lo split ----------------
__global__ void dequant_kernel(const u32* __restrict__ qw, const float* __restrict__ alpha,
                               const float* __restrict__ beta, const int* __restrict__ inv_out,
                               const int* __restrict__ bbw,
                               u16* __restrict__ wth, u16* __restrict__ wtl) {
  const int nc = blockIdx.x;
  const int kw = threadIdx.x;          // 0..127 : word index along k
  const int n = inv_out[nc];
  const int g = kw >> 2;
  const int nb = bbw[g * 128 + (n >> 5)];
  const float a = alpha[g * N_DIM + n];
  const float bt = beta[g * N_DIM + n];
  const u32 q0 = qw[(kw * 4 + 0) * N_DIM + n];
  u32 q1 = qw[(kw * 4 + 1) * N_DIM + n];
  u32 q2 = qw[(kw * 4 + 2) * N_DIM + n];
  u32 q3 = qw[(kw * 4 + 3) * N_DIM + n];
  q1 = (nb > 1) ? q1 : 0u;
  q2 = (nb > 2) ? q2 : 0u;
  q3 = (nb > 3) ? q3 : 0u;
  const float a2 = 2.0f * a;
  const float offs = bt - a * (float)((1 << nb) - 1);

  __align__(16) u32 oh[16], ol[16];
#pragma unroll
  for (int j = 0; j < 16; ++j) { oh[j] = 0u; ol[j] = 0u; }
#pragma unroll
  for (int j = 0; j < 32; ++j) {
    u32 val = ((q0 >> j) & 1u) | (((q1 >> j) & 1u) << 1) |
              (((q2 >> j) & 1u) << 2) | (((q3 >> j) & 1u) << 3);
    float wv = a2 * (float)val + offs;
    u16 h = f2bf(wv);
    u16 l = f2bf(wv - bf2f(h));
    oh[j >> 1] |= ((u32)h) << ((j & 1) * 16);
    ol[j >> 1] |= ((u32)l) << ((j & 1) * 16);
  }
  long basee = (long)nc * K_DIM + kw * 32;
  uint4* dh = (uint4*)&wth[basee];
  uint4* dl = (uint4*)&wtl[basee];
#pragma unroll
  for (int i = 0; i < 4; ++i) {
    dh[i] = ((const uint4*)oh)[i];
    dl[i] = ((const uint4*)ol)[i];
  }
}

// ---------------- GEMM: 256x256 tile, 4-phase pipelined schedule ----------------
// LDS: A[2buf][2half][128*64] + B[2buf][2half][128*64] u16 = 128 KiB.
// Phase p of tile t: {ds_reads; stage 1 half; vmcnt(4); s_barrier; 16 MFMA}.
// Stage stream (sigma=6 halves ahead, half order per tile = B0,B1,A0,A1):
//   p0 -> A0(t+1), p1 -> A1(t+1), p2 -> B0(t+2), p3 -> B1(t+2)
// Slot-safety ledger (last read -> restage issue, all separated by >=1 barrier):
//   A0/A1(t-1) read thru (t-1).p2 -> staged t.p0/t.p1   OK
//   B0(t) read at t.p0 only      -> staged t.p2          OK
//   B1(t) read at t.p1 only      -> staged t.p3          OK
// vmcnt(4) at phase phi retires stage pairs issued <= phi-2 => halves <= phi+4 landed;
// tile t needs halves <= 4t+3 at entry (prev sync phi=4t-1 guarantees exactly that).

#define VMCNT4 asm volatile("s_waitcnt vmcnt(4)" ::: "memory")
#define BARRIER asm volatile("s_barrier" ::: "memory")

#define STAGE_HALF(SRC, DST) {                                            \
    load_lds16((SRC) + (long)((0 * 8 + wave) * 8 + rlane) * K_DIM + kswz, \
               (DST) + (0 * 8 + wave) * 512);                             \
    load_lds16((SRC) + (long)((1 * 8 + wave) * 8 + rlane) * K_DIM + kswz, \
               (DST) + (1 * 8 + wave) * 512); }

#define LDA(MQ) { _Pragma("unroll") for (int i = 0; i < 4; ++i) {         \
      const int rh = ((MQ) * 4 + i) * 16 + fr;                            \
      const u16* rp = Ah + rh * 64;                                       \
      a[i * 2 + 0] = *(const bf16x8*)(rp + ((fkf + 0) ^ swz));            \
      a[i * 2 + 1] = *(const bf16x8*)(rp + ((fkf + 32) ^ swz)); } }

#define LDB(BR, NQ) { _Pragma("unroll") for (int i = 0; i < 2; ++i) {     \
      const int ch = bq + ((NQ) * 2 + i) * 16 + fr;                       \
      const u16* cp = Bh + ch * 64;                                       \
      BR[i * 2 + 0] = *(const bf16x8*)(cp + ((fkf + 0) ^ swz));           \
      BR[i * 2 + 1] = *(const bf16x8*)(cp + ((fkf + 32) ^ swz)); } }

#define MMQUAD(MQ, NQ, BR)                                                \
    __builtin_amdgcn_s_setprio(1);                                        \
    _Pragma("unroll") for (int i = 0; i < 4; ++i) {                       \
      acc[(MQ)*4+i][(NQ)*2+0] = __builtin_amdgcn_mfma_f32_16x16x32_bf16(  \
          a[i*2+0], BR[0], acc[(MQ)*4+i][(NQ)*2+0], 0, 0, 0);             \
      acc[(MQ)*4+i][(NQ)*2+0] = __builtin_amdgcn_mfma_f32_16x16x32_bf16(  \
          a[i*2+1], BR[1], acc[(MQ)*4+i][(NQ)*2+0], 0, 0, 0);             \
      acc[(MQ)*4+i][(NQ)*2+1] = __builtin_amdgcn_mfma_f32_16x16x32_bf16(  \
          a[i*2+0], BR[2], acc[(MQ)*4+i][(NQ)*2+1], 0, 0, 0);             \
      acc[(MQ)*4+i][(NQ)*2+1] = __builtin_amdgcn_mfma_f32_16x16x32_bf16(  \
          a[i*2+1], BR[3], acc[(MQ)*4+i][(NQ)*2+1], 0, 0, 0);             \
    }                                                                     \
    __builtin_amdgcn_s_setprio(0);

__global__ __launch_bounds__(512, 2)
void gemm_kernel(const u16* __restrict__ xh, const u16* __restrict__ xl,
                 const u16* __restrict__ wth, const u16* __restrict__ wtl,
                 float* __restrict__ out) {
  __shared__ __align__(16) u16 lds[65536];   // 128 KiB

  const int tid = threadIdx.x;
  const int lane = tid & 63;
  const int wave = tid >> 6;
  const int wm = wave >> 2;        // 0..1 : wave row-half
  const int wn = wave & 3;         // 0..3 : wave col-quarter

  // XCD-aware block swizzle (nwg=512, 512%8==0 -> simple variant is bijective)
  const int bid = blockIdx.x;
  const int sb = (bid & 7) * 64 + (bid >> 3);
  const long brow = (long)(sb >> 4) * 256;   // 32 row-tiles
  const long bcol = (long)(sb & 15) * 256;   // 16 col-tiles

  // staging constants (write side: linear LDS dest, pre-swizzled global src)
  const int rlane = lane >> 3;
  const int kswz = ((lane & 7) ^ (lane >> 3)) * 8;
  // read-side fragment constants
  const int fr = lane & 15;
  const int fkf = (lane >> 4) * 8;
  const int swz = (fr & 7) << 3;
  const int bq = (wn & 1) * 64;

  f32x4 acc[8][4];
  const f32x4 zero = {0.f, 0.f, 0.f, 0.f};
#pragma unroll
  for (int i = 0; i < 8; ++i)
#pragma unroll
    for (int j = 0; j < 4; ++j) acc[i][j] = zero;

  // ---- prologue: stage halves 0..5 = B0(0),B1(0),A0(0),A1(0),B0(1),B1(1) ----
  {
    u16* Ad0 = &lds[0];
    u16* Bd0 = &lds[32768];
    u16* Bd1 = &lds[32768 + 16384];
    STAGE_HALF(wth + bcol * K_DIM, Bd0);                     // B0(0)
    STAGE_HALF(wth + (bcol + 128) * K_DIM, Bd0 + 8192);      // B1(0)
    STAGE_HALF(xh + brow * K_DIM, Ad0);                      // A0(0)
    STAGE_HALF(xh + (brow + 128) * K_DIM, Ad0 + 8192);       // A1(0)
    STAGE_HALF(wth + bcol * K_DIM + 64, Bd1);                // B0(1)  (kt=1)
    STAGE_HALF(wth + (bcol + 128) * K_DIM + 64, Bd1 + 8192); // B1(1)
  }
  VMCNT4;
  BARRIER;

  for (int t = 0; t < NTILES; ++t) {
    const int cb = t & 1;
    const u16* Ah = &lds[cb * 16384 + wm * 8192];
    const u16* Bh = &lds[32768 + cb * 16384 + (wn >> 1) * 8192];

    // stage targets: A of tile t+1, B of tile t+2 (phantom-wrap past NTILES)
    int tnA = t + 1; if (tnA >= NTILES) tnA -= NTILES;
    int tnB = t + 2; if (tnB >= NTILES) tnB -= NTILES;
    const int segA = tnA >> 6, ktA = tnA & 63;
    const int segB = tnB >> 6, ktB = tnB & 63;
    const u16* Ap = (segA == 1) ? xl : xh;
    const u16* Bp = (segB == 2) ? wtl : wth;
    const u16* As0 = Ap + brow * K_DIM + ktA * 64;
    const u16* As1 = Ap + (brow + 128) * K_DIM + ktA * 64;
    const u16* Bs0 = Bp + bcol * K_DIM + ktB * 64;
    const u16* Bs1 = Bp + (bcol + 128) * K_DIM + ktB * 64;
    u16* Ad = &lds[((t + 1) & 1) * 16384];
    u16* Bd = &lds[32768 + ((t + 2) & 1) * 16384];

    bf16x8 a[8], b0[4], b1[4];

    // -- phase 0: A quad0 + B pair0 reads; stage A0(t+1); MFMA (m0-3, n0-1)
    LDA(0);
    LDB(b0, 0);
    STAGE_HALF(As0, Ad);
    VMCNT4;
    BARRIER;
    MMQUAD(0, 0, b0);

    // -- phase 1: B pair1 reads; stage A1(t+1); MFMA (m0-3, n2-3)
    LDB(b1, 1);
    STAGE_HALF(As1, Ad + 8192);
    VMCNT4;
    BARRIER;
    MMQUAD(0, 1, b1);

    // -- phase 2: A quad1 reads; stage B0(t+2); MFMA (m4-7, n2-3)
    LDA(1);
    STAGE_HALF(Bs0, Bd);
    VMCNT4;
    BARRIER;
    MMQUAD(1, 1, b1);

    // -- phase 3: no reads; stage B1(t+2); MFMA (m4-7, n0-1)
    STAGE_HALF(Bs1, Bd + 8192);
    VMCNT4;
    BARRIER;
    MMQUAD(1, 0, b0);
  }

  // drain phantom stages before LDS dealloc / epilogue
  asm volatile("s_waitcnt vmcnt(0)" ::: "memory");

  // epilogue: C/D layout col=lane&15, row=(lane>>4)*4+r
  const int orow = (lane >> 4) * 4;
  const int ocol = lane & 15;
#pragma unroll
  for (int m = 0; m < 8; ++m)
#pragma unroll
    for (int n = 0; n < 4; ++n) {
      const long r0 = brow + wm * 128 + m * 16 + orow;
      const long c0 = bcol + wn * 64 + n * 16 + ocol;
#pragma unroll
      for (int r = 0; r < 4; ++r)
        out[(r0 + r) * N_DIM + c0] = acc[m][n][r];
    }
}

extern "C" void kernel_launch(void* const* d_in, const int* in_sizes, int n_in,
                              void* d_out, int out_size, void* d_ws, size_t ws_size,
                              hipStream_t stream) {
  const float* x = (const float*)d_in[0];
  const u32* qweight = (const u32*)d_in[1];
  const float* alpha = (const float*)d_in[2];
  const float* beta = (const float*)d_in[3];
  const int* in_reorder = (const int*)d_in[4];
  const int* out_reorder = (const int*)d_in[5];
  const int* bbw = (const int*)d_in[6];
  float* out = (float*)d_out;

  char* ws = (char*)d_ws;
  u16* xh = (u16*)(ws);                               // 64 MiB
  u16* xl = (u16*)(ws + ((size_t)64 << 20));          // 64 MiB
  u16* wth = (u16*)(ws + ((size_t)128 << 20));        // 32 MiB
  u16* wtl = (u16*)(ws + ((size_t)160 << 20));        // 32 MiB
  int* inv_out = (int*)(ws + ((size_t)192 << 20));    // 16 KiB

  hipLaunchKernelGGL(invert_kernel, dim3(16), dim3(256), 0, stream, out_reorder, inv_out);
  hipLaunchKernelGGL(convert_x_kernel, dim3(M_DIM), dim3(256), 0, stream, x, in_reorder, xh, xl);
  hipLaunchKernelGGL(dequant_kernel, dim3(N_DIM), dim3(128), 0, stream,
                     qweight, alpha, beta, inv_out, bbw, wth, wtl);
  hipLaunchKernelGGL(gemm_kernel, dim3((M_DIM / 256) * (N_DIM / 256)), dim3(512), 0, stream,
                     xh, xl, wth, wtl, out);
}

// Round 5
// 687.355 us; speedup vs baseline: 1.9170x; 1.3427x over previous
//
#include <hip/hip_runtime.h>

// BCQ (LUT-GEMM style) linear: out[:, out_reorder] = x[:, in_reorder] @ W
// W[k,n] = alpha[k/128, n] * wsum[k,n] + beta[k/128, n]
// Split-precision bf16 MFMA GEMM, 2 segments: y = xh@Wh + xl@Wh  (Wl dropped; the
// comparison error is dominated by the reference's own matmul rounding — see journal).
// GEMM = 256x256 tile, BK=64, 8 waves, 4-phase/K-tile schedule with counted vmcnt(4),
// T2 LDS XOR-swizzle, T5 setprio, T1 XCD swizzle. Race ledger in comments below.

typedef unsigned short u16;
typedef unsigned int u32;
typedef __attribute__((ext_vector_type(8))) short bf16x8;
typedef __attribute__((ext_vector_type(4))) float f32x4;

#define M_DIM 8192
#define K_DIM 4096
#define N_DIM 4096
#define NTILES 128   // 2 segments * (4096/64)

__device__ __forceinline__ u16 f2bf(float f) {
  u32 u = __float_as_uint(f);
  u32 r = (u + 0x7fffu + ((u >> 16) & 1u)) >> 16;   // RNE
  return (u16)r;
}
__device__ __forceinline__ float bf2f(u16 h) { return __uint_as_float(((u32)h) << 16); }

__device__ __forceinline__ void load_lds16(const void* g, void* l) {
  __builtin_amdgcn_global_load_lds((const __attribute__((address_space(1))) void*)g,
                                   (__attribute__((address_space(3))) void*)l, 16, 0, 0);
}

// ---------------- inverse permutation of out_reorder ----------------
__global__ void invert_kernel(const int* __restrict__ out_reorder, int* __restrict__ inv_out) {
  int i = blockIdx.x * 256 + threadIdx.x;
  if (i < N_DIM) inv_out[out_reorder[i]] = i;
}

// ---------------- x gather (in_reorder) + bf16 hi/lo split ----------------
// Row staged in LDS via coalesced float4 loads; gather hits LDS (random ds_read_b32,
// ~2-way conflicts = free per m136). xh[m][k] = bf16(x[m][inr[k]]), xl = residual.
__global__ __launch_bounds__(256)
void convert_x_kernel(const float* __restrict__ x, const int* __restrict__ inr,
                      u16* __restrict__ xh, u16* __restrict__ xl) {
  __shared__ float xs[K_DIM];
  const int m = blockIdx.x;
  const float4* __restrict__ src = (const float4*)(x + (long)m * K_DIM);
#pragma unroll
  for (int i = 0; i < 4; ++i)
    ((float4*)xs)[threadIdx.x + i * 256] = src[threadIdx.x + i * 256];
  __syncthreads();
#pragma unroll
  for (int it = 0; it < 2; ++it) {
    const int base = (threadIdx.x + it * 256) * 8;
    const int4 i0 = *(const int4*)&inr[base];
    const int4 i1 = *(const int4*)&inr[base + 4];
    u32 oh[4], ol[4];
    const int idx[8] = {i0.x, i0.y, i0.z, i0.w, i1.x, i1.y, i1.z, i1.w};
#pragma unroll
    for (int i = 0; i < 8; ++i) {
      float v = xs[idx[i]];
      u16 h = f2bf(v);
      u16 l = f2bf(v - bf2f(h));
      if ((i & 1) == 0) { oh[i >> 1] = (u32)h; ol[i >> 1] = (u32)l; }
      else { oh[i >> 1] |= ((u32)h) << 16; ol[i >> 1] |= ((u32)l) << 16; }
    }
    long o = (long)m * K_DIM + base;
    *(uint4*)&xh[o] = *(const uint4*)oh;
    *(uint4*)&xl[o] = *(const uint4*)ol;
  }
}

// ---------------- W dequant into K-major, out-permuted, bf16 (hi only) ----------------
__global__ void dequant_kernel(const u32* __restrict__ qw, const float* __restrict__ alpha,
                               const float* __restrict__ beta, const int* __restrict__ inv_out,
                               const int* __restrict__ bbw, u16* __restrict__ wth) {
  const int nc = blockIdx.x;
  const int kw = threadIdx.x;          // 0..127 : word index along k
  const int n = inv_out[nc];
  const int g = kw >> 2;
  const int nb = bbw[g * 128 + (n >> 5)];
  const float a = alpha[g * N_DIM + n];
  const float bt = beta[g * N_DIM + n];
  const u32 q0 = qw[(kw * 4 + 0) * N_DIM + n];
  u32 q1 = qw[(kw * 4 + 1) * N_DIM + n];
  u32 q2 = qw[(kw * 4 + 2) * N_DIM + n];
  u32 q3 = qw[(kw * 4 + 3) * N_DIM + n];
  q1 = (nb > 1) ? q1 : 0u;
  q2 = (nb > 2) ? q2 : 0u;
  q3 = (nb > 3) ? q3 : 0u;
  const float a2 = 2.0f * a;
  const float offs = bt - a * (float)((1 << nb) - 1);

  __align__(16) u32 oh[16];
#pragma unroll
  for (int j = 0; j < 16; ++j) oh[j] = 0u;
#pragma unroll
  for (int j = 0; j < 32; ++j) {
    u32 val = ((q0 >> j) & 1u) | (((q1 >> j) & 1u) << 1) |
              (((q2 >> j) & 1u) << 2) | (((q3 >> j) & 1u) << 3);
    float wv = a2 * (float)val + offs;
    oh[j >> 1] |= ((u32)f2bf(wv)) << ((j & 1) * 16);
  }
  long basee = (long)nc * K_DIM + kw * 32;
  uint4* dh = (uint4*)&wth[basee];
#pragma unroll
  for (int i = 0; i < 4; ++i) dh[i] = ((const uint4*)oh)[i];
}

// ---------------- GEMM: 256x256 tile, 4-phase pipelined schedule ----------------
// LDS: A[2buf][2half][128*64] + B[2buf][2half][128*64] u16 = 128 KiB.
// Phase p of tile t: {ds_reads; stage 1 half; vmcnt(4); s_barrier; 16 MFMA}.
// Stage stream (6 halves ahead, half order per tile = B0,B1,A0,A1):
//   p0 -> A0(t+1), p1 -> A1(t+1), p2 -> B0(t+2), p3 -> B1(t+2)
// Slot-safety ledger (last read -> restage issue, all separated by >=1 barrier):
//   A0/A1(t-1) read thru (t-1).p2 -> staged t.p0/t.p1   OK
//   B0(t) read at t.p0 only      -> staged t.p2          OK
//   B1(t) read at t.p1 only      -> staged t.p3          OK
// vmcnt(4) at phase phi retires stage pairs issued <= phi-2 => halves <= phi+4 landed;
// tile t needs halves <= 4t+3 at entry (prev sync phi=4t-1 guarantees exactly that).

#define VMCNT4 asm volatile("s_waitcnt vmcnt(4)" ::: "memory")
#define BARRIER asm volatile("s_barrier" ::: "memory")

#define STAGE_HALF(SRC, DST) {                                            \
    load_lds16((SRC) + (long)((0 * 8 + wave) * 8 + rlane) * K_DIM + kswz, \
               (DST) + (0 * 8 + wave) * 512);                             \
    load_lds16((SRC) + (long)((1 * 8 + wave) * 8 + rlane) * K_DIM + kswz, \
               (DST) + (1 * 8 + wave) * 512); }

#define LDA(MQ) { _Pragma("unroll") for (int i = 0; i < 4; ++i) {         \
      const int rh = ((MQ) * 4 + i) * 16 + fr;                            \
      const u16* rp = Ah + rh * 64;                                       \
      a[i * 2 + 0] = *(const bf16x8*)(rp + ((fkf + 0) ^ swz));            \
      a[i * 2 + 1] = *(const bf16x8*)(rp + ((fkf + 32) ^ swz)); } }

#define LDB(BR, NQ) { _Pragma("unroll") for (int i = 0; i < 2; ++i) {     \
      const int ch = bq + ((NQ) * 2 + i) * 16 + fr;                       \
      const u16* cp = Bh + ch * 64;                                       \
      BR[i * 2 + 0] = *(const bf16x8*)(cp + ((fkf + 0) ^ swz));           \
      BR[i * 2 + 1] = *(const bf16x8*)(cp + ((fkf + 32) ^ swz)); } }

#define MMQUAD(MQ, NQ, BR)                                                \
    __builtin_amdgcn_s_setprio(1);                                        \
    _Pragma("unroll") for (int i = 0; i < 4; ++i) {                       \
      acc[(MQ)*4+i][(NQ)*2+0] = __builtin_amdgcn_mfma_f32_16x16x32_bf16(  \
          a[i*2+0], BR[0], acc[(MQ)*4+i][(NQ)*2+0], 0, 0, 0);             \
      acc[(MQ)*4+i][(NQ)*2+0] = __builtin_amdgcn_mfma_f32_16x16x32_bf16(  \
          a[i*2+1], BR[1], acc[(MQ)*4+i][(NQ)*2+0], 0, 0, 0);             \
      acc[(MQ)*4+i][(NQ)*2+1] = __builtin_amdgcn_mfma_f32_16x16x32_bf16(  \
          a[i*2+0], BR[2], acc[(MQ)*4+i][(NQ)*2+1], 0, 0, 0);             \
      acc[(MQ)*4+i][(NQ)*2+1] = __builtin_amdgcn_mfma_f32_16x16x32_bf16(  \
          a[i*2+1], BR[3], acc[(MQ)*4+i][(NQ)*2+1], 0, 0, 0);             \
    }                                                                     \
    __builtin_amdgcn_s_setprio(0);

__global__ __launch_bounds__(512, 2)
void gemm_kernel(const u16* __restrict__ xh, const u16* __restrict__ xl,
                 const u16* __restrict__ wth, float* __restrict__ out) {
  __shared__ __align__(16) u16 lds[65536];   // 128 KiB

  const int tid = threadIdx.x;
  const int lane = tid & 63;
  const int wave = tid >> 6;
  const int wm = wave >> 2;        // 0..1 : wave row-half
  const int wn = wave & 3;         // 0..3 : wave col-quarter

  // XCD-aware block swizzle (nwg=512, 512%8==0 -> simple variant is bijective)
  const int bid = blockIdx.x;
  const int sb = (bid & 7) * 64 + (bid >> 3);
  const long brow = (long)(sb >> 4) * 256;   // 32 row-tiles
  const long bcol = (long)(sb & 15) * 256;   // 16 col-tiles

  // staging constants (write side: linear LDS dest, pre-swizzled global src)
  const int rlane = lane >> 3;
  const int kswz = ((lane & 7) ^ (lane >> 3)) * 8;
  // read-side fragment constants
  const int fr = lane & 15;
  const int fkf = (lane >> 4) * 8;
  const int swz = (fr & 7) << 3;
  const int bq = (wn & 1) * 64;

  f32x4 acc[8][4];
  const f32x4 zero = {0.f, 0.f, 0.f, 0.f};
#pragma unroll
  for (int i = 0; i < 8; ++i)
#pragma unroll
    for (int j = 0; j < 4; ++j) acc[i][j] = zero;

  // ---- prologue: stage halves 0..5 = B0(0),B1(0),A0(0),A1(0),B0(1),B1(1) ----
  {
    u16* Ad0 = &lds[0];
    u16* Bd0 = &lds[32768];
    u16* Bd1 = &lds[32768 + 16384];
    STAGE_HALF(wth + bcol * K_DIM, Bd0);                     // B0(0)
    STAGE_HALF(wth + (bcol + 128) * K_DIM, Bd0 + 8192);      // B1(0)
    STAGE_HALF(xh + brow * K_DIM, Ad0);                      // A0(0)
    STAGE_HALF(xh + (brow + 128) * K_DIM, Ad0 + 8192);       // A1(0)
    STAGE_HALF(wth + bcol * K_DIM + 64, Bd1);                // B0(1)  (kt=1)
    STAGE_HALF(wth + (bcol + 128) * K_DIM + 64, Bd1 + 8192); // B1(1)
  }
  VMCNT4;
  BARRIER;

  for (int t = 0; t < NTILES; ++t) {
    const int cb = t & 1;
    const u16* Ah = &lds[cb * 16384 + wm * 8192];
    const u16* Bh = &lds[32768 + cb * 16384 + (wn >> 1) * 8192];

    // stage targets: A of tile t+1, B of tile t+2 (phantom-wrap past NTILES)
    int tnA = t + 1; if (tnA >= NTILES) tnA -= NTILES;
    int tnB = t + 2; if (tnB >= NTILES) tnB -= NTILES;
    const int ktA = tnA & 63;
    const int ktB = tnB & 63;
    const u16* Ap = (tnA & 64) ? xl : xh;   // segment 0: xh, segment 1: xl
    const u16* As0 = Ap + brow * K_DIM + ktA * 64;
    const u16* As1 = Ap + (brow + 128) * K_DIM + ktA * 64;
    const u16* Bs0 = wth + bcol * K_DIM + ktB * 64;          // B is wth both segments
    const u16* Bs1 = wth + (bcol + 128) * K_DIM + ktB * 64;
    u16* Ad = &lds[((t + 1) & 1) * 16384];
    u16* Bd = &lds[32768 + ((t + 2) & 1) * 16384];

    bf16x8 a[8], b0[4], b1[4];

    // -- phase 0: A quad0 + B pair0 reads; stage A0(t+1); MFMA (m0-3, n0-1)
    LDA(0);
    LDB(b0, 0);
    STAGE_HALF(As0, Ad);
    VMCNT4;
    BARRIER;
    MMQUAD(0, 0, b0);

    // -- phase 1: B pair1 reads; stage A1(t+1); MFMA (m0-3, n2-3)
    LDB(b1, 1);
    STAGE_HALF(As1, Ad + 8192);
    VMCNT4;
    BARRIER;
    MMQUAD(0, 1, b1);

    // -- phase 2: A quad1 reads; stage B0(t+2); MFMA (m4-7, n2-3)
    LDA(1);
    STAGE_HALF(Bs0, Bd);
    VMCNT4;
    BARRIER;
    MMQUAD(1, 1, b1);

    // -- phase 3: no reads; stage B1(t+2); MFMA (m4-7, n0-1)
    STAGE_HALF(Bs1, Bd + 8192);
    VMCNT4;
    BARRIER;
    MMQUAD(1, 0, b0);
  }

  // drain phantom stages before LDS dealloc / epilogue
  asm volatile("s_waitcnt vmcnt(0)" ::: "memory");

  // epilogue: C/D layout col=lane&15, row=(lane>>4)*4+r
  const int orow = (lane >> 4) * 4;
  const int ocol = lane & 15;
#pragma unroll
  for (int m = 0; m < 8; ++m)
#pragma unroll
    for (int n = 0; n < 4; ++n) {
      const long r0 = brow + wm * 128 + m * 16 + orow;
      const long c0 = bcol + wn * 64 + n * 16 + ocol;
#pragma unroll
      for (int r = 0; r < 4; ++r)
        out[(r0 + r) * N_DIM + c0] = acc[m][n][r];
    }
}

extern "C" void kernel_launch(void* const* d_in, const int* in_sizes, int n_in,
                              void* d_out, int out_size, void* d_ws, size_t ws_size,
                              hipStream_t stream) {
  const float* x = (const float*)d_in[0];
  const u32* qweight = (const u32*)d_in[1];
  const float* alpha = (const float*)d_in[2];
  const float* beta = (const float*)d_in[3];
  const int* in_reorder = (const int*)d_in[4];
  const int* out_reorder = (const int*)d_in[5];
  const int* bbw = (const int*)d_in[6];
  float* out = (float*)d_out;

  char* ws = (char*)d_ws;
  u16* xh = (u16*)(ws);                               // 64 MiB
  u16* xl = (u16*)(ws + ((size_t)64 << 20));          // 64 MiB
  u16* wth = (u16*)(ws + ((size_t)128 << 20));        // 32 MiB
  int* inv_out = (int*)(ws + ((size_t)160 << 20));    // 16 KiB

  hipLaunchKernelGGL(invert_kernel, dim3(16), dim3(256), 0, stream, out_reorder, inv_out);
  hipLaunchKernelGGL(convert_x_kernel, dim3(M_DIM), dim3(256), 0, stream, x, in_reorder, xh, xl);
  hipLaunchKernelGGL(dequant_kernel, dim3(N_DIM), dim3(128), 0, stream,
                     qweight, alpha, beta, inv_out, bbw, wth);
  hipLaunchKernelGGL(gemm_kernel, dim3((M_DIM / 256) * (N_DIM / 256)), dim3(512), 0, stream,
                     xh, xl, wth, out);
}